// Round 5
// baseline (246.782 us; speedup 1.0000x reference)
//
#include <hip/hip_runtime.h>

// spike_seq: (T=1024, B=16384, 2) fp32; w_exc={0.7,1.0}; w_inh=-1.0.
// Outputs flat: spk_rec (T*B) then mem_rec (T*B), fp32.
#define T_LEN 1024
#define B_N   16384
#define PH    16              // timesteps per phase
#define NPH   (T_LEN / PH)    // 64 phases
// Round-4 result: loader->LDS->compute->LDS->storer pipeline landed at the
// same 82us as the single-wave ping-pong => limiter is per-CU outstanding-op
// depth (Little's law: ~24KB loads in flight + 1 wave of stores = the
// observed 2.6 B/cyc/CU), not op count and not store-ack chaining per se.
// This version maximizes MLP:
//   wave0 compute: own global loads (ping-pong reg buffers; its vmcnt domain
//                  has NO stores, so load waits never chain behind acks),
//                  neuron math, ds_write results to a 4-deep OUT ring.
//   waves1-3 storers: round-robin phases; 3x outstanding-store capacity;
//                  each has 3 phase-times to drain 8KB fire-and-forget.
// Raw s_barrier + lgkmcnt(0) only — no vmcnt drain anywhere in the loop.

__shared__ __align__(16) float2 OUT_lds[4][PH][64];   // 32 KiB ring

static __device__ __forceinline__ void block_barrier() {
  asm volatile("" ::: "memory");          // compiler fence: no mem-op motion
  __builtin_amdgcn_s_barrier();
  asm volatile("" ::: "memory");
}

__global__ __launch_bounds__(256, 1) void FMFMNeuronInhib_34033320854098_kernel(
    const float* __restrict__ x,      // (T, B, 2)
    const float* __restrict__ w_exc,  // {0.7, 1.0}
    const float* __restrict__ w_inh,  // {-1.0}
    float* __restrict__ out) {
#pragma clang fp contract(off)
  const int lane = threadIdx.x & 63;
  const int wid  = threadIdx.x >> 6;      // 0=compute, 1..3=storers
  const int nb0  = blockIdx.x * 64;       // this block's first neuron

  float* __restrict__ spk_out = out;
  float* __restrict__ mem_out = out + (size_t)T_LEN * B_N;

  if (wid == 0) {
    // ---------------- compute (loads + math + LDS handoff) ----------------
    const float w0 = w_exc[0];
    const float w1 = w_exc[1];
    const float wi = w_inh[0];
    const float2* __restrict__ xp = (const float2*)x + nb0 + lane;  // + t*B_N
    float mem = 0.0f, inh = 0.0f;

    float2 bufA[PH], bufB[PH];
    // Prologue: phases 0 and 1 in flight (32 loads, 16KB).
#pragma unroll
    for (int u = 0; u < PH; ++u) bufA[u] = xp[(size_t)u * B_N];
#pragma unroll
    for (int u = 0; u < PH; ++u) bufB[u] = xp[(size_t)(PH + u) * B_N];
    __builtin_amdgcn_sched_barrier(0);

    auto phase = [&](float2 (&buf)[PH], int p) {
#pragma clang fp contract(off)
      // Consume (compiler inserts progressive vmcnt waits; only loads are in
      // this wave's domain, so the wait is pure load latency).
#pragma unroll
      for (int u = 0; u < PH; ++u) {
        const float x0 = buf[u].x;
        const float x1 = buf[u].y;
        // Exact reference op order; no FMA contraction (1-ulp flips a spike).
        const float cur_exc = x0 * w0 + x1 * w1;    // x @ w_exc^T
        inh = 0.6f * inh + x0;                      // inh decay + feed
        const float cur = cur_exc + wi * inh;       // wi = -1.0 exact
        // (mem-1>0) == (mem>1) exactly; reset*1.0f == reset.
        const float reset = (mem > 1.0f) ? 1.0f : 0.0f;
        mem = 0.9f * mem + cur - reset;
        const float spk = (mem > 1.0f) ? 1.0f : 0.0f;
        OUT_lds[p & 3][u][lane] = make_float2(spk, mem);
      }
      __builtin_amdgcn_sched_barrier(0);
      // Refill this buffer with phase p+2 (WAR safe: VALU reads retired at
      // issue; loads land asynchronously, waited at next consumption).
      if (p + 2 < NPH) {
#pragma unroll
        for (int u = 0; u < PH; ++u)
          buf[u] = xp[(size_t)((p + 2) * PH + u) * B_N];
      }
      __builtin_amdgcn_sched_barrier(0);
      asm volatile("s_waitcnt lgkmcnt(0)" ::: "memory");  // ds_writes visible
      block_barrier();
    };

    for (int p = 0; p < NPH; p += 2) {
      phase(bufA, p);
      phase(bufB, p + 1);
    }
  } else {
    // ---------------- storers (round-robin over phases) ----------------
    const int sid = wid - 1;  // 0..2
    auto drain = [&](int p) {
      const int tb = p * PH;
      const int slot = p & 3;
#pragma unroll
      for (int u = 0; u < PH; ++u) {
        const float2 v = OUT_lds[slot][u][lane];
        const size_t idx = (size_t)(tb + u) * B_N + nb0 + lane;
        spk_out[idx] = v.x;   // 256B/row/block, globally coalesced
        mem_out[idx] = v.y;
      }
      // No waits: stores are fire-and-forget in this wave's own vmcnt
      // domain; ds_read completion is forced by the store data dependency
      // before the wave reaches the next barrier (in-order issue).
    };
    for (int p = 0; p < NPH; ++p) {
      if (p >= 1 && ((p - 1) % 3) == sid) drain(p - 1);
      block_barrier();
    }
    if ((NPH - 1) % 3 == sid) drain(NPH - 1);  // final phase, after last barrier
  }
}

extern "C" void kernel_launch(void* const* d_in, const int* in_sizes, int n_in,
                              void* d_out, int out_size, void* d_ws, size_t ws_size,
                              hipStream_t stream) {
  const float* x     = (const float*)d_in[0];  // spike_seq, T*B*2 floats
  const float* w_exc = (const float*)d_in[1];  // 2 floats
  const float* w_inh = (const float*)d_in[2];  // 1 float
  float* out = (float*)d_out;                  // spk_rec ++ mem_rec

  dim3 grid(B_N / 64);   // 256 blocks -> 1 block (4 waves, 1/SIMD) per CU
  dim3 block(256);       // wave0 compute, waves1-3 storers
  hipLaunchKernelGGL(FMFMNeuronInhib_34033320854098_kernel, grid, block, 0, stream,
                     x, w_exc, w_inh, out);
}

// Round 6
// 243.470 us; speedup vs baseline: 1.0136x; 1.0136x over previous
//
#include <hip/hip_runtime.h>

// spike_seq: (T=1024, B=16384, 2) fp32; w_exc={0.7,1.0}; w_inh=-1.0.
// Outputs flat: spk_rec (T*B) then mem_rec (T*B), fp32.
#define T_LEN 1024
#define B_N   16384
#define PH    16              // timesteps per phase
#define NPH   (T_LEN / PH)    // 64 phases
#define RIN   5               // IN ring depth  (40 KiB)
#define ROUT  2               // OUT ring depth (16 KiB)
#define WGSC  __HIP_MEMORY_SCOPE_WORKGROUP

// R0-R5 evidence: every structure lands at 80-105us / ~2.4 TB/s because
// per-CU in-flight bytes are capped (~8-12KB) by (a) the compiler collapsing
// register prefetch buffers (VGPR_Count=44 twice) and (b) s_barrier lockstep
// throttling the loader to the consumer's pace. This version removes both:
//   - IN ring lives in LDS, filled via global_load_lds (no VGPR dest =>
//     compiler cannot collapse it); loader runs up to RIN-1 phases ahead with
//     counted vmcnt(32) waits => ~32-40KB of loads in flight per CU.
//   - ZERO s_barrier. Wave coupling via LDS flag counters using
//     workgroup-scope acquire/release atomics: release on LDS emits
//     s_waitcnt lgkmcnt(0) + ds_write only — vmcnt is never drained, so
//     handshakes don't flush the load pipeline.
// Roles (4 waves = 1/SIMD): w1 loader -> IN ring -> w0 compute (pure
// VALU+LDS, zero vmem in its domain) -> OUT ring -> w2/w3 storers
// (parity-split; stores fire-and-forget in their own vmcnt domains).

__shared__ __align__(16) float2 IN_lds[RIN][PH][64];    // 40 KiB
__shared__ __align__(16) float2 OUT_lds[ROUT][PH][64];  // 16 KiB
// F[0]=prod_in (phases landed in IN ring)     writer: loader
// F[1]=cons_in (phases consumed from IN ring) writer: compute
// F[2]=prod_out (phases written to OUT ring)  writer: compute
// F[3]=cons_out even / F[4]=cons_out odd      writers: storer 0 / storer 1
__shared__ int F[8];

static __device__ __forceinline__ int ld_flag(int i) {
  return __hip_atomic_load(&F[i], __ATOMIC_ACQUIRE, WGSC);
}
static __device__ __forceinline__ void st_flag(int i, int v) {
  __hip_atomic_store(&F[i], v, __ATOMIC_RELEASE, WGSC);
}

__global__ __launch_bounds__(256, 1) void FMFMNeuronInhib_34033320854098_kernel(
    const float* __restrict__ x,      // (T, B, 2)
    const float* __restrict__ w_exc,  // {0.7, 1.0}
    const float* __restrict__ w_inh,  // {-1.0}
    float* __restrict__ out) {
#pragma clang fp contract(off)
  const int lane = threadIdx.x & 63;
  const int wid  = threadIdx.x >> 6;   // 0=compute, 1=loader, 2/3=storers
  const int nb0  = blockIdx.x * 64;    // this block's first neuron

  if (threadIdx.x < 8) F[threadIdx.x] = 0;
  __syncthreads();  // once, at start: nothing in flight yet

  float* __restrict__ spk_out = out;
  float* __restrict__ mem_out = out + (size_t)T_LEN * B_N;

  if (wid == 1) {
    // ---------------- loader ----------------
    // Phase p slice: rows t = p*PH..p*PH+15, 512B per row. One dwordx4
    // global_load_lds covers 2 rows (1KB): lanes 0-31 row 2j, 32-63 row 2j+1.
    // LDS dest = wave-uniform base + lane*16 (linear layout, matches ring).
    const int half = lane >> 5;
    const int l32  = lane & 31;
    for (int p = 0; p < NPH; ++p) {
      // Ring backpressure: slot p%RIN last used by phase p-RIN; need it
      // consumed (cons_in >= p-RIN+1). No spin for p < RIN.
      while (ld_flag(1) < p - (RIN - 1)) __builtin_amdgcn_s_sleep(1);
      const int slot = p % RIN;
#pragma unroll
      for (int j = 0; j < 8; ++j) {
        const int t = p * PH + 2 * j + half;
        const float* src = x + ((size_t)t * B_N + nb0) * 2 + (size_t)l32 * 4;
        __builtin_amdgcn_global_load_lds(
            (const __attribute__((address_space(1))) void*)src,
            (__attribute__((address_space(3))) void*)&IN_lds[slot][2 * j][0],
            16, 0, 0);
      }
      if (p >= 4) {
        // Keep newest 4 phases (32 ops) unconfirmed in flight; oldest landed.
        asm volatile("s_waitcnt vmcnt(32)" ::: "memory");
        if (lane == 0) st_flag(0, p - 3);
      }
    }
    asm volatile("s_waitcnt vmcnt(0)" ::: "memory");
    if (lane == 0) st_flag(0, NPH);
  } else if (wid == 0) {
    // ---------------- compute: pure VALU + LDS ----------------
    const float w0 = w_exc[0];
    const float w1 = w_exc[1];
    const float wi = w_inh[0];
    float mem = 0.0f, inh = 0.0f;
    for (int p = 0; p < NPH; ++p) {
      while (ld_flag(0) < p + 1) __builtin_amdgcn_s_sleep(1);
      const int islot = p % RIN;
      float2 xv[PH];
#pragma unroll
      for (int u = 0; u < PH; ++u) xv[u] = IN_lds[islot][u][lane];
      // Release store waits lgkmcnt(0): all 16 ds_reads retired -> slot free.
      if (lane == 0) st_flag(1, p + 1);

      float sv[PH], mv[PH];
#pragma unroll
      for (int u = 0; u < PH; ++u) {
        const float x0 = xv[u].x;
        const float x1 = xv[u].y;
        // Exact reference op order; no FMA contraction (1 ulp flips a spike).
        const float cur_exc = x0 * w0 + x1 * w1;   // x @ w_exc^T
        inh = 0.6f * inh + x0;                     // inh decay + feed
        const float cur = cur_exc + wi * inh;      // wi = -1.0 exact
        // (mem-1>0) == (mem>1) exactly; reset*1.0f == reset.
        const float reset = (mem > 1.0f) ? 1.0f : 0.0f;
        mem = 0.9f * mem + cur - reset;
        sv[u] = (mem > 1.0f) ? 1.0f : 0.0f;
        mv[u] = mem;
      }
      // OUT slot p%ROUT last used by phase p-ROUT (same parity as p; its
      // storer publishes cons_out[p&1] = p-ROUT+1). Wait until drained.
      if (p >= ROUT)
        while (ld_flag(3 + (p & 1)) < p - 1) __builtin_amdgcn_s_sleep(1);
      const int oslot = p % ROUT;
#pragma unroll
      for (int u = 0; u < PH; ++u)
        OUT_lds[oslot][u][lane] = make_float2(sv[u], mv[u]);
      // Release waits lgkmcnt(0): ds_writes visible before flag.
      if (lane == 0) st_flag(2, p + 1);
    }
  } else {
    // ---------------- storers (parity-split) ----------------
    const int sid = wid - 2;  // 0 handles even phases, 1 odd
    for (int p = sid; p < NPH; p += 2) {
      while (ld_flag(2) < p + 1) __builtin_amdgcn_s_sleep(1);
      const int oslot = p & 1;  // == p % ROUT
      const int tb = p * PH;
#pragma unroll
      for (int u = 0; u < PH; ++u) {
        const float2 v = OUT_lds[oslot][u][lane];
        const size_t idx = (size_t)(tb + u) * B_N + nb0 + lane;
        spk_out[idx] = v.x;   // 256B/row/block, globally coalesced
        mem_out[idx] = v.y;
      }
      // Release waits lgkmcnt(0) (ds_reads retired -> slot reusable). The
      // global stores hold their data already; acks drain in this wave's own
      // vmcnt domain, off every other wave's critical path.
      if (lane == 0) st_flag(3 + sid, p + 1);
    }
  }
}

extern "C" void kernel_launch(void* const* d_in, const int* in_sizes, int n_in,
                              void* d_out, int out_size, void* d_ws, size_t ws_size,
                              hipStream_t stream) {
  const float* x     = (const float*)d_in[0];  // spike_seq, T*B*2 floats
  const float* w_exc = (const float*)d_in[1];  // 2 floats
  const float* w_inh = (const float*)d_in[2];  // 1 float
  float* out = (float*)d_out;                  // spk_rec ++ mem_rec

  dim3 grid(B_N / 64);   // 256 blocks -> 1 block (4 waves, 1/SIMD) per CU
  dim3 block(256);       // w0 compute, w1 loader, w2/w3 storers
  hipLaunchKernelGGL(FMFMNeuronInhib_34033320854098_kernel, grid, block, 0, stream,
                     x, w_exc, w_inh, out);
}

// Round 7
// 229.514 us; speedup vs baseline: 1.0752x; 1.0608x over previous
//
#include <hip/hip_runtime.h>

// spike_seq: (T=1024, B=16384, 2) fp32; w_exc={0.7,1.0}; w_inh=-1.0.
// Outputs flat: spk_rec (T*B) then mem_rec (T*B), fp32.
#define T_LEN 1024
#define B_N   16384
#define PH    16              // timesteps per phase
#define NPH   (T_LEN / PH)    // 64
#define RIN   4               // IN ring depth (32 KiB)

// R0-R6 evidence: every structure (reg ping-pong, 3-wave barrier pipeline,
// flag-decoupled 40KB-deep ring) lands at 81-105us / 2.0-2.5 TB/s, while
// fillBufferAligned hits 6.6 TB/s at the SAME vmem wave-instruction rate
// (~1 instr / 90 cyc / CU) using 1KB dwordx4 stores vs our 256B dword
// stores. Conclusion: per-CU vmem INSTRUCTION rate is the cap; the lever is
// bytes/instruction. This version packs output stores to dwordx4 (1KB/instr,
// 4 rows per instruction) via an LDS transpose:
//   compute writes spk & mem to separate float planes [PH][64];
//   storer lane L reads float4 = 4 adjacent neurons of row (L>>4) and one
//   global_store_dwordx4 covers 4 rows. 8 store instr/phase instead of 32.
// Waves: w0 compute (pure VALU+LDS), w1 loader (global_load_lds dwordx4,
// counted vmcnt, 3 phases ahead), w2 spk-storer, w3 mem-storer.
// Raw s_barrier + lgkmcnt waits only; no vmcnt drain in the loop except the
// loader's counted (never-zero) waits.

__shared__ __align__(16) float2 IN_lds[RIN][PH][64];  // 32 KiB input ring
__shared__ __align__(16) float  SPK_lds[2][PH][64];   // 8 KiB
__shared__ __align__(16) float  MEM_lds[2][PH][64];   // 8 KiB

static __device__ __forceinline__ void block_barrier() {
  asm volatile("" ::: "memory");   // compiler fence: no mem-op motion
  __builtin_amdgcn_s_barrier();
  asm volatile("" ::: "memory");
}

__global__ __launch_bounds__(256, 1) void FMFMNeuronInhib_34033320854098_kernel(
    const float* __restrict__ x,      // (T, B, 2)
    const float* __restrict__ w_exc,  // {0.7, 1.0}
    const float* __restrict__ w_inh,  // {-1.0}
    float* __restrict__ out) {
#pragma clang fp contract(off)
  const int lane = threadIdx.x & 63;
  const int wid  = threadIdx.x >> 6;   // 0=compute 1=loader 2=spk-st 3=mem-st
  const int nb0  = blockIdx.x * 64;    // this block's first neuron

  float* __restrict__ spk_out = out;
  float* __restrict__ mem_out = out + (size_t)T_LEN * B_N;

  if (wid == 1) {
    // ---------------- loader ----------------
    // Phase p: rows t=p*PH..p*PH+15, 512B/row. One dwordx4 global_load_lds
    // covers 2 rows (1KB): lanes 0-31 row 2j, lanes 32-63 row 2j+1. LDS dest
    // is wave-uniform base + lane*16 (linear, matches [PH][64]float2 rows).
    const int half = lane >> 5;
    const int l32  = lane & 31;
    auto issue_phase = [&](int q) {
#pragma unroll
      for (int j = 0; j < 8; ++j) {
        const int t = q * PH + 2 * j + half;
        const float* src = x + ((size_t)t * B_N + nb0) * 2 + (size_t)l32 * 4;
        __builtin_amdgcn_global_load_lds(
            (const __attribute__((address_space(1))) void*)src,
            (__attribute__((address_space(3))) void*)&IN_lds[q & 3][2 * j][0],
            16, 0, 0);
      }
    };
    issue_phase(0); issue_phase(1); issue_phase(2);   // 24 ops in flight
    asm volatile("s_waitcnt vmcnt(16)" ::: "memory"); // phase 0 landed
    block_barrier();
    for (int p = 0; p < NPH; ++p) {
      if (p + 3 < NPH) issue_phase(p + 3);  // slot (p-1)&3: freed at barrier p-1
      // Guarantee phase p+1 landed before barrier p; keep younger phases
      // (p+2, p+3: 16 ops) in flight — counted wait, never 0 mid-loop.
      if (p <= NPH - 4)      asm volatile("s_waitcnt vmcnt(16)" ::: "memory");
      else if (p == NPH - 3) asm volatile("s_waitcnt vmcnt(8)"  ::: "memory");
      else                   asm volatile("s_waitcnt vmcnt(0)"  ::: "memory");
      block_barrier();
    }
  } else if (wid == 0) {
    // ---------------- compute: pure VALU + LDS ----------------
    const float w0 = w_exc[0];
    const float w1 = w_exc[1];
    const float wi = w_inh[0];
    float mem = 0.0f, inh = 0.0f;
    block_barrier();                                  // prologue barrier
    for (int p = 0; p < NPH; ++p) {
      float2 xv[PH];
#pragma unroll
      for (int u = 0; u < PH; ++u) xv[u] = IN_lds[p & 3][u][lane];
#pragma unroll
      for (int u = 0; u < PH; ++u) {
        const float x0 = xv[u].x;
        const float x1 = xv[u].y;
        // Exact reference op order; no FMA contraction (1 ulp flips a spike).
        const float cur_exc = x0 * w0 + x1 * w1;   // x @ w_exc^T
        inh = 0.6f * inh + x0;                     // inh decay + feed
        const float cur = cur_exc + wi * inh;      // wi = -1.0 exact
        // (mem-1>0) == (mem>1) exactly; reset*1.0f == reset.
        const float reset = (mem > 1.0f) ? 1.0f : 0.0f;
        mem = 0.9f * mem + cur - reset;
        const float spk = (mem > 1.0f) ? 1.0f : 0.0f;
        SPK_lds[p & 1][u][lane] = spk;             // separate planes so the
        MEM_lds[p & 1][u][lane] = mem;             // storer can read float4
      }
      // All ds_reads (IN slot reusable) and ds_writes (visible to storers)
      // retired before the barrier.
      asm volatile("s_waitcnt lgkmcnt(0)" ::: "memory");
      block_barrier();
    }
  } else {
    // ---------------- storers: packed dwordx4, one plane each ----------------
    const float* plane = (wid == 2) ? &SPK_lds[0][0][0] : &MEM_lds[0][0][0];
    float* gout        = (wid == 2) ? spk_out : mem_out;
    const int r  = lane >> 4;          // row within group of 4
    const int n0 = (lane & 15) * 4;    // 4 adjacent neurons
    auto drain = [&](int p) {
      const int tb   = p * PH;
      const int slot = p & 1;
#pragma unroll
      for (int j = 0; j < 4; ++j) {    // 4 instr cover 16 rows
        const int row = 4 * j + r;
        const float4 v =
            *(const float4*)(plane + ((size_t)slot * PH + row) * 64 + n0);
        *(float4*)&gout[(size_t)(tb + row) * B_N + nb0 + n0] = v;
      }
      // ds_reads retired -> compute may overwrite this slot next phase.
      // Global stores fire-and-forget in this wave's own vmcnt domain.
      asm volatile("s_waitcnt lgkmcnt(0)" ::: "memory");
    };
    block_barrier();                                  // prologue barrier
    for (int p = 0; p < NPH; ++p) {
      if (p >= 1) drain(p - 1);  // reads slot (p-1)&1 while compute writes p&1
      block_barrier();
    }
    drain(NPH - 1);  // final phase, ordered by the last in-loop barrier
  }
}

extern "C" void kernel_launch(void* const* d_in, const int* in_sizes, int n_in,
                              void* d_out, int out_size, void* d_ws, size_t ws_size,
                              hipStream_t stream) {
  const float* x     = (const float*)d_in[0];  // spike_seq, T*B*2 floats
  const float* w_exc = (const float*)d_in[1];  // 2 floats
  const float* w_inh = (const float*)d_in[2];  // 1 float
  float* out = (float*)d_out;                  // spk_rec ++ mem_rec

  dim3 grid(B_N / 64);   // 256 blocks -> 1 block (4 waves, 1/SIMD) per CU
  dim3 block(256);       // w0 compute, w1 loader, w2 spk-storer, w3 mem-storer
  hipLaunchKernelGGL(FMFMNeuronInhib_34033320854098_kernel, grid, block, 0, stream,
                     x, w_exc, w_inh, out);
}